// Round 1
// baseline (374.669 us; speedup 1.0000x reference)
//
#include <hip/hip_runtime.h>

// PPAModel: node encoder (2-layer MLP) -> edge gather/concat -> edge MLP -> sigmoid
// IN=128, HID=256, OUT=128, N_NODES=100000, N_EDGES=1000000
//
// ws layout (needs ~25.9 MB):
//   [0,256)            : int flag (1 => edge_index stored as int64)
//   [256, +64KB)       : W1 bf16 swizzled  [k/8][n][k%8], K=128,N=256
//   [65792, +64KB)     : W2 bf16 swizzled  K=256,N=128
//   [131328, +128KB)   : W3 bf16 swizzled  K=256,N=256
//   [262400, +25.6MB)  : h table bf16 [100000][128]

#define NN 100000
#define NE 1000000

typedef __attribute__((ext_vector_type(8))) __bf16 bf16x8;
typedef __attribute__((ext_vector_type(4))) float f32x4;
typedef __attribute__((ext_vector_type(4))) unsigned short us4;

__device__ __forceinline__ unsigned short f2bf(float f) {
    unsigned u = __float_as_uint(f);
    return (unsigned short)((u + 0x7FFFu + ((u >> 16) & 1u)) >> 16);
}

#define GLD16(g, l)                                                         \
    __builtin_amdgcn_global_load_lds(                                       \
        (__attribute__((address_space(1))) void*)(g),                       \
        (__attribute__((address_space(3))) void*)(l), 16, 0, 0)

// ---------------- prep: swizzle weights to bf16, detect index dtype -------
__global__ void prep_kernel(const float* __restrict__ W1,
                            const float* __restrict__ W2,
                            const float* __restrict__ W3,
                            const void* __restrict__ eidx,
                            unsigned short* __restrict__ w1s,
                            unsigned short* __restrict__ w2s,
                            unsigned short* __restrict__ w3s,
                            int* __restrict__ flag) {
    int t = blockIdx.x * blockDim.x + threadIdx.x;
    if (t < 32768) {                       // W1: K=128, N=256
        int k = t >> 8, n = t & 255;
        w1s[(k >> 3) * 2048 + n * 8 + (k & 7)] = f2bf(W1[t]);
    } else if (t < 65536) {                // W2: K=256, N=128
        int i = t - 32768;
        int k = i >> 7, n = i & 127;
        w2s[(k >> 3) * 1024 + n * 8 + (k & 7)] = f2bf(W2[i]);
    } else if (t < 131072) {               // W3: K=256, N=256
        int i = t - 65536;
        int k = i >> 8, n = i & 255;
        w3s[(k >> 3) * 2048 + n * 8 + (k & 7)] = f2bf(W3[i]);
    }
    if (t == 0) {
        // int64 little-endian: every high word of the first 32 indices is 0.
        const unsigned* u = (const unsigned*)eidx;
        int all0 = 1;
        for (int i = 0; i < 32; ++i) all0 &= (u[2 * i + 1] == 0u);
        *flag = all0;
    }
}

// ---------------- phase 1: fused node encoder -----------------------------
// per block: 64 nodes. GEMM1 [64x128]x[128x256] +b1,relu -> GEMM2 [64x256]x[256x128] +b2 -> h bf16
__global__ __launch_bounds__(256, 1) void node_enc(
    const float* __restrict__ x, const float* __restrict__ b1,
    const float* __restrict__ b2, const unsigned short* __restrict__ w1s,
    const unsigned short* __restrict__ w2s, unsigned short* __restrict__ hbf) {
    __shared__ __align__(16) char lds[148480];
    unsigned short* A1 = (unsigned short*)(lds);            // 64 x (128+8) bf16 = 17408 B
    unsigned short* B1 = (unsigned short*)(lds + 17408);    // W1 64KB
    unsigned short* B2 = (unsigned short*)(lds + 82944);    // W2 64KB
    unsigned short* A2 = (unsigned short*)(lds);            // 64 x (256+8) bf16 = 33792 B (reuses A1+B1 head)

    const int t = threadIdx.x, lane = t & 63, w = t >> 6;
    const int cl = lane & 15, q = lane >> 4;
    const int m0 = blockIdx.x * 64;

    // async stage W1, W2 (already bf16-swizzled, contiguous)
    {
        const char* g1 = (const char*)w1s + w * 16384;
        const char* g2 = (const char*)w2s + w * 16384;
        char* l1 = lds + 17408 + w * 16384;
        char* l2 = lds + 82944 + w * 16384;
#pragma unroll
        for (int i = 0; i < 16; ++i) {
            GLD16(g1 + i * 1024 + lane * 16, l1 + i * 1024);
            GLD16(g2 + i * 1024 + lane * 16, l2 + i * 1024);
        }
    }
    // stage A1: x rows f32 -> bf16, row stride 136 elem (272 B, bank offset 4)
    {
        const float4* x4 = (const float4*)x;
#pragma unroll
        for (int i = 0; i < 8; ++i) {
            int lin = i * 256 + t;
            int m = lin >> 5, c = lin & 31;
            int node = m0 + m;
            if (node > NN - 1) node = NN - 1;
            float4 v = x4[node * 32 + c];
            us4 b;
            b.x = f2bf(v.x); b.y = f2bf(v.y); b.z = f2bf(v.z); b.w = f2bf(v.w);
            *(us4*)(A1 + m * 136 + c * 4) = b;
        }
    }
    __syncthreads();

    // GEMM1: each wave owns 64 N-cols
    f32x4 acc[4][4];
#pragma unroll
    for (int i = 0; i < 4; ++i)
#pragma unroll
        for (int j = 0; j < 4; ++j) acc[i][j] = (f32x4)0.0f;
    const int nb = w * 64;
#pragma unroll
    for (int s = 0; s < 4; ++s) {   // K=128, 4 steps of 32
        bf16x8 a[4], b[4];
#pragma unroll
        for (int mt = 0; mt < 4; ++mt)
            a[mt] = *(const bf16x8*)(A1 + (mt * 16 + cl) * 136 + s * 32 + q * 8);
#pragma unroll
        for (int nt = 0; nt < 4; ++nt)
            b[nt] = *(const bf16x8*)(B1 + (s * 4 + q) * 2048 + (nb + nt * 16 + cl) * 8);
#pragma unroll
        for (int mt = 0; mt < 4; ++mt)
#pragma unroll
            for (int nt = 0; nt < 4; ++nt)
                acc[mt][nt] = __builtin_amdgcn_mfma_f32_16x16x32_bf16(a[mt], b[nt], acc[mt][nt], 0, 0, 0);
    }
    __syncthreads();   // everyone done reading A1/B1 before overwrite with A2

    // +b1, relu, write A2 [m][k] bf16, row stride 264 elem
    {
        float b1v[4];
#pragma unroll
        for (int nt = 0; nt < 4; ++nt) b1v[nt] = b1[nb + nt * 16 + cl];
#pragma unroll
        for (int mt = 0; mt < 4; ++mt)
#pragma unroll
            for (int nt = 0; nt < 4; ++nt)
#pragma unroll
                for (int r = 0; r < 4; ++r) {
                    float v = acc[mt][nt][r] + b1v[nt];
                    v = fmaxf(v, 0.0f);
                    A2[(mt * 16 + q * 4 + r) * 264 + nb + nt * 16 + cl] = f2bf(v);
                }
    }
    __syncthreads();

    // GEMM2: [64x256] x [256x128]; each wave owns 32 N-cols
    f32x4 acc2[4][2];
#pragma unroll
    for (int i = 0; i < 4; ++i)
#pragma unroll
        for (int j = 0; j < 2; ++j) acc2[i][j] = (f32x4)0.0f;
    const int nb2 = w * 32;
#pragma unroll
    for (int s = 0; s < 8; ++s) {   // K=256
        bf16x8 a[4], b[2];
#pragma unroll
        for (int mt = 0; mt < 4; ++mt)
            a[mt] = *(const bf16x8*)(A2 + (mt * 16 + cl) * 264 + s * 32 + q * 8);
#pragma unroll
        for (int nt = 0; nt < 2; ++nt)
            b[nt] = *(const bf16x8*)(B2 + (s * 4 + q) * 1024 + (nb2 + nt * 16 + cl) * 8);
#pragma unroll
        for (int mt = 0; mt < 4; ++mt)
#pragma unroll
            for (int nt = 0; nt < 2; ++nt)
                acc2[mt][nt] = __builtin_amdgcn_mfma_f32_16x16x32_bf16(a[mt], b[nt], acc2[mt][nt], 0, 0, 0);
    }
    // +b2 -> h table (bf16)
    {
        float b2v[2];
#pragma unroll
        for (int nt = 0; nt < 2; ++nt) b2v[nt] = b2[nb2 + nt * 16 + cl];
#pragma unroll
        for (int mt = 0; mt < 4; ++mt)
#pragma unroll
            for (int nt = 0; nt < 2; ++nt)
#pragma unroll
                for (int r = 0; r < 4; ++r) {
                    int node = m0 + mt * 16 + q * 4 + r;
                    if (node < NN)
                        hbf[node * 128 + nb2 + nt * 16 + cl] =
                            f2bf(acc2[mt][nt][r] + b2v[nt]);
                }
    }
}

// ---------------- phase 2: edge MLP (gather + GEMM + fused head) ----------
// per block: 64 edges. A = [h_src|h_dst] bf16 in LDS (stride 264), B = W3 from
// swizzled global (register frags), epilogue: +b3, relu, dot W4, +b4, sigmoid.
__global__ __launch_bounds__(256, 2) void edge_mlp(
    const void* __restrict__ eidx, const unsigned short* __restrict__ hbf,
    const unsigned short* __restrict__ w3s, const float* __restrict__ b3,
    const float* __restrict__ W4, const float* __restrict__ b4,
    const int* __restrict__ flag, float* __restrict__ out) {
    __shared__ __align__(16) unsigned short A[64 * 264];  // 33792 B
    __shared__ float partial[4][64];

    const int t = threadIdx.x, lane = t & 63, w = t >> 6;
    const int cl = lane & 15, q = lane >> 4;
    const int blk = blockIdx.x;
    const bool i64 = (*flag != 0);
    const int* ei32 = (const int*)eidx;
    const long long* ei64 = (const long long*)eidx;

    // gather 64 edge rows (src half k=0..127, dst half k=128..255)
#pragma unroll
    for (int i = 0; i < 8; ++i) {
        int lin = i * 256 + t;
        int m = lin >> 5, c = lin & 31;   // c: 16B chunk within 512B row
        int e = blk * 64 + m;
        int eoff = (c < 16) ? e : (NE + e);
        int node = i64 ? (int)ei64[eoff] : ei32[eoff];
        if (node < 0) node = 0;
        if (node > NN - 1) node = NN - 1;
        uint4 v = *(const uint4*)(hbf + node * 128 + (c & 15) * 8);
        *(uint4*)(A + m * 264 + ((c < 16) ? 0 : 128) + (c & 15) * 8) = v;
    }
    __syncthreads();

    f32x4 acc[4][4];
#pragma unroll
    for (int i = 0; i < 4; ++i)
#pragma unroll
        for (int j = 0; j < 4; ++j) acc[i][j] = (f32x4)0.0f;
    const int nb = w * 64;
#pragma unroll
    for (int s = 0; s < 8; ++s) {   // K=256, 8 steps of 32
        bf16x8 a[4], b[4];
#pragma unroll
        for (int mt = 0; mt < 4; ++mt)
            a[mt] = *(const bf16x8*)(A + (mt * 16 + cl) * 264 + s * 32 + q * 8);
#pragma unroll
        for (int nt = 0; nt < 4; ++nt)
            b[nt] = *(const bf16x8*)(w3s + (s * 4 + q) * 2048 + (nb + nt * 16 + cl) * 8);
#pragma unroll
        for (int mt = 0; mt < 4; ++mt)
#pragma unroll
            for (int nt = 0; nt < 4; ++nt)
                acc[mt][nt] = __builtin_amdgcn_mfma_f32_16x16x32_bf16(a[mt], b[nt], acc[mt][nt], 0, 0, 0);
    }

    // epilogue: hidden = relu(acc + b3); p = hidden . W4   (per edge row)
    float b3v[4], w4v[4];
#pragma unroll
    for (int nt = 0; nt < 4; ++nt) {
        int n = nb + nt * 16 + cl;
        b3v[nt] = b3[n];
        w4v[nt] = W4[n];
    }
    float p[4][4];
#pragma unroll
    for (int mt = 0; mt < 4; ++mt)
#pragma unroll
        for (int r = 0; r < 4; ++r) {
            float s = 0.0f;
#pragma unroll
            for (int nt = 0; nt < 4; ++nt) {
                float h = acc[mt][nt][r] + b3v[nt];
                h = fmaxf(h, 0.0f);
                s += h * w4v[nt];
            }
            p[mt][r] = s;
        }
    // reduce across the 16 lanes (cl) holding different n for the same row
#pragma unroll
    for (int off = 1; off < 16; off <<= 1)
#pragma unroll
        for (int mt = 0; mt < 4; ++mt)
#pragma unroll
            for (int r = 0; r < 4; ++r)
                p[mt][r] += __shfl_xor(p[mt][r], off, 64);
    if (cl == 0) {
#pragma unroll
        for (int mt = 0; mt < 4; ++mt)
#pragma unroll
            for (int r = 0; r < 4; ++r)
                partial[w][mt * 16 + q * 4 + r] = p[mt][r];
    }
    __syncthreads();
    if (t < 64) {
        float logit = partial[0][t] + partial[1][t] + partial[2][t] +
                      partial[3][t] + b4[0];
        out[blk * 64 + t] = 1.0f / (1.0f + __expf(-logit));
    }
}

extern "C" void kernel_launch(void* const* d_in, const int* in_sizes, int n_in,
                              void* d_out, int out_size, void* d_ws, size_t ws_size,
                              hipStream_t stream) {
    const float* x  = (const float*)d_in[0];
    const void*  ei = d_in[1];
    const float* W1 = (const float*)d_in[2];
    const float* b1 = (const float*)d_in[3];
    const float* W2 = (const float*)d_in[4];
    const float* b2 = (const float*)d_in[5];
    const float* W3 = (const float*)d_in[6];
    const float* b3 = (const float*)d_in[7];
    const float* W4 = (const float*)d_in[8];
    const float* b4 = (const float*)d_in[9];

    char* ws = (char*)d_ws;
    int* flag            = (int*)ws;
    unsigned short* w1s  = (unsigned short*)(ws + 256);
    unsigned short* w2s  = (unsigned short*)(ws + 256 + 65536);
    unsigned short* w3s  = (unsigned short*)(ws + 256 + 131072);
    unsigned short* hbf  = (unsigned short*)(ws + 256 + 262144);

    prep_kernel<<<512, 256, 0, stream>>>(W1, W2, W3, ei, w1s, w2s, w3s, flag);
    node_enc<<<(NN + 63) / 64, 256, 0, stream>>>(x, b1, b2, w1s, w2s, hbf);
    edge_mlp<<<NE / 64, 256, 0, stream>>>(ei, hbf, w3s, b3, W4, b4, flag, (float*)d_out);
}